// Round 2
// baseline (162.930 us; speedup 1.0000x reference)
//
#include <hip/hip_runtime.h>

// MultiScaleTrendLoss: loss = mean_{b,f} sum_a w_a * mean_t EMA_a(pred-target)[b,t,f]^2
// EMA linearity: EMA(pred)-EMA(target) == EMA(pred-target) (same y0 = x0 init).
//
// Parallelization: 64 lanes = 64 features (coalesced 256B row reads).
// Time axis (4096) split into 16 chunks of 256 with 128-step zero-carry
// warm-up (truncation error (0.9)^128 ~ 1.4e-6 relative -- negligible).
// Grid = 64 batches x 16 chunks = 1024 one-wave blocks (4 waves/CU).

#define T_LEN   4096
#define F_LEN   64
#define NCHUNK  16
#define CHUNK   256
#define WARM    128

__global__ __launch_bounds__(64)
void MultiScaleTrendLoss_910533067632_kernel(const float* __restrict__ pred,
                                             const float* __restrict__ targ,
                                             float* __restrict__ out)
{
    const int f = threadIdx.x;            // feature 0..63
    const int b = blockIdx.x >> 4;        // batch 0..63
    const int c = blockIdx.x & (NCHUNK - 1);
    const int t0 = c * CHUNK;

    float e0 = 0.f, e1 = 0.f, e2 = 0.f;   // EMA states (alpha = .1/.3/.5)
    float s0 = 0.f, s1 = 0.f, s2 = 0.f;   // sum of squares per alpha

    const int tstart = (c == 0) ? 0 : (t0 - WARM);
    const float* __restrict__ p = pred + ((size_t)b * T_LEN + tstart) * F_LEN + f;
    const float* __restrict__ q = targ + ((size_t)b * T_LEN + tstart) * F_LEN + f;

    if (c == 0) {
        // t = 0: y[0] = x[0] exactly
        float d = *p - *q; p += F_LEN; q += F_LEN;
        e0 = d; e1 = d; e2 = d;
        float dd = d * d;
        s0 = dd; s1 = dd; s2 = dd;
        #pragma unroll 8
        for (int i = 1; i < CHUNK; ++i) {
            float dv = *p - *q; p += F_LEN; q += F_LEN;
            e0 = fmaf(0.9f, e0, 0.1f * dv);
            e1 = fmaf(0.7f, e1, 0.3f * dv);
            e2 = fmaf(0.5f, e2, 0.5f * dv);
            s0 = fmaf(e0, e0, s0);
            s1 = fmaf(e1, e1, s1);
            s2 = fmaf(e2, e2, s2);
        }
    } else {
        // zero-carry warm-up (no accumulation)
        #pragma unroll 8
        for (int i = 0; i < WARM; ++i) {
            float dv = *p - *q; p += F_LEN; q += F_LEN;
            e0 = fmaf(0.9f, e0, 0.1f * dv);
            e1 = fmaf(0.7f, e1, 0.3f * dv);
            e2 = fmaf(0.5f, e2, 0.5f * dv);
        }
        #pragma unroll 8
        for (int i = 0; i < CHUNK; ++i) {
            float dv = *p - *q; p += F_LEN; q += F_LEN;
            e0 = fmaf(0.9f, e0, 0.1f * dv);
            e1 = fmaf(0.7f, e1, 0.3f * dv);
            e2 = fmaf(0.5f, e2, 0.5f * dv);
            s0 = fmaf(e0, e0, s0);
            s1 = fmaf(e1, e1, s1);
            s2 = fmaf(e2, e2, s2);
        }
    }

    // weighted combine, then wave-64 butterfly reduce
    float s = 0.5f * s0 + 0.3f * s1 + 0.2f * s2;
    #pragma unroll
    for (int off = 32; off > 0; off >>= 1)
        s += __shfl_down(s, off, 64);

    if (f == 0) {
        // mean over 64*4096*64 = 16777216 elements
        atomicAdd(out, s * (1.0f / 16777216.0f));
    }
}

extern "C" void kernel_launch(void* const* d_in, const int* in_sizes, int n_in,
                              void* d_out, int out_size, void* d_ws, size_t ws_size,
                              hipStream_t stream) {
    const float* pred = (const float*)d_in[0];
    const float* targ = (const float*)d_in[1];
    float* out = (float*)d_out;

    // d_out is poisoned 0xAA before every call -- zero it (atomicAdd target)
    hipMemsetAsync(out, 0, sizeof(float) * out_size, stream);

    dim3 grid(64 * NCHUNK);
    dim3 block(64);
    MultiScaleTrendLoss_910533067632_kernel<<<grid, block, 0, stream>>>(pred, targ, out);
}